// Round 6
// baseline (179.890 us; speedup 1.0000x reference)
//
#include <hip/hip_runtime.h>

#define T_ 12
#define N_ 1370
#define LDA 88       // row stride in shorts (176B): ≤2-way banks on b128
#define NBLK 1370    // 87680 / 64 seqs per block (2 groups x 32)

typedef __attribute__((ext_vector_type(8))) short short8;
typedef __attribute__((ext_vector_type(4))) float floatx4;

#define NLOG2E -1.4426950408889634f
#define TLOG2E 2.8853900817779268f

__device__ __forceinline__ short f2bf(float x) {
  unsigned u = __builtin_bit_cast(unsigned, x);
  u = (u + 0x7fffu + ((u >> 16) & 1u)) >> 16;
  return (short)u;
}
__device__ __forceinline__ unsigned pk_bf16(float a, float b) {
  unsigned r;
  asm("v_cvt_pk_bf16_f32 %0, %1, %2" : "=v"(r) : "v"(a), "v"(b));
  return r;
}
__device__ __forceinline__ short8 load_w8s(const float* __restrict__ p, float s) {
  short8 r;
#pragma unroll
  for (int j = 0; j < 8; ++j) r[j] = f2bf(p[j] * s);
  return r;
}

// Block = 64 seqs as TWO independent groups of 32 (shared weights -> weight
// prologue amortized 2x; one barrier per step covers both groups; 2x
// independent work per wave fills MFMA/trans latency). Per group: swapped-
// operand MFMA, A = weights (m = gate row), B = row [h(0..63)|x_t(64..71)|
// 1.0(72)|pad] (n = seq). Chunk2 A rows: q=0 -> W_ih, q=1 j=0 -> scaled
// bias, others ZERO -> pad/overrun B data multiplied by zero = harmless.
// x in registers (12 bf16 in 6 VGPRs per group-slot per thread), dropped
// into the write buffer per step. D: col=lane&15 = seq, row=q*4+r = unit ->
// i/f/g/o of a cell share reg r; c stays fp32 in regs; h writeback = one
// ds_write_b64. Scales pre-folded: i,f,o by -log2e (sigma = 1/(1+2^y)),
// g by 2*log2e (tanh = 1 - 2/(1+2^y)); one v_rcp per cell's 4 gates.
// (256,4): (256,5) spilled in R4; R5 compiled at 56 VGPR so headroom exists.
__global__ void __launch_bounds__(256, 4) lstm_kernel(
    const float* __restrict__ x, const float* __restrict__ W_ih,
    const float* __restrict__ W_hh, const float* __restrict__ b_ih,
    const float* __restrict__ b_hh, const float* __restrict__ W_fc,
    const float* __restrict__ b_fc, float* __restrict__ out) {
  __shared__ short hbuf[2 * 2 * 32 * LDA + 8];  // [grp][buf][row][LDA] + pad

  const int tid = threadIdx.x;
  const int wave = tid >> 6;
  const int lane = tid & 63;
  const int m16 = lane & 15;
  const int q = lane >> 4;
  const int blk = blockIdx.x;

#define HROW(G, B, R) (&hbuf[(((G)*2 + (B)) * 32 + (R)) * LDA])

  // ---- x -> registers: thread stages (seq row tid>>3, col tid&7) for both
  // groups: group A seq = blk*64 + row, group B seq = blk*64 + 32 + row ----
  const int xseq = tid >> 3, xc = tid & 7;
  unsigned xpkA[6], xpkB[6];
  {
#pragma unroll
    for (int g2 = 0; g2 < 2; ++g2) {
      const int s0 = blk * 64 + g2 * 32 + xseq;
      const int bidx = s0 / N_;
      const int nidx = s0 - bidx * N_;
      const float* xp = x + ((size_t)(bidx * T_) * N_ + nidx) * 8 + xc;
      float xv[T_];
#pragma unroll
      for (int t = 0; t < T_; ++t) xv[t] = xp[(size_t)t * (N_ * 8)];
      unsigned* dst = g2 ? xpkB : xpkA;
#pragma unroll
      for (int i = 0; i < 6; ++i) dst[i] = pk_bf16(xv[2 * i], xv[2 * i + 1]);
    }
  }

  // ---- A-operand weight fragments (shared by both groups) ----
  const int urow = wave * 16 + m16;
  short8 wA[4][3];
#pragma unroll
  for (int g = 0; g < 4; ++g) {
    const float sg = (g == 2) ? TLOG2E : NLOG2E;
    const int grow = g * 64 + urow;
    const float* wr = W_hh + grow * 64;
    wA[g][0] = load_w8s(wr + q * 8, sg);
    wA[g][1] = load_w8s(wr + 32 + q * 8, sg);
    short8 z = {0, 0, 0, 0, 0, 0, 0, 0};
    if (q == 0) {
      wA[g][2] = load_w8s(W_ih + grow * 8, sg);      // k = 64..71: x cols
    } else if (q == 1) {
      z[0] = f2bf(sg * (b_ih[grow] + b_hh[grow]));   // k = 72: bias col
      wA[g][2] = z;
    } else {
      wA[g][2] = z;                                  // k = 80..95 dead
    }
  }

  // ---- zero LDS (h0 = 0), then bias columns + x_0 ----
  {
    int* hp = (int*)hbuf;
#pragma unroll
    for (int i = tid; i < (2 * 2 * 32 * LDA + 8) / 2; i += 256) hp[i] = 0;
  }
  __syncthreads();
  if (tid < 128)
    HROW(tid >> 6, (tid >> 5) & 1, tid & 31)[72] = (short)0x3F80;  // 1.0
  HROW(0, 0, xseq)[64 + xc] = (short)xpkA[0];
  HROW(1, 0, xseq)[64 + xc] = (short)xpkB[0];
  __syncthreads();

  const floatx4 zacc = {0.0f, 0.0f, 0.0f, 0.0f};
  float cst[2][2][4];
#pragma unroll
  for (int g2 = 0; g2 < 2; ++g2)
#pragma unroll
    for (int nt = 0; nt < 2; ++nt)
#pragma unroll
      for (int r = 0; r < 4; ++r) cst[g2][nt][r] = 0.0f;

#define TILE(G, NT, rb, wb)                                                    \
  do {                                                                         \
    const int srow = (NT)*16 + m16;                                            \
    const short* base = HROW((G), (rb), srow);                                 \
    short8 b0 = *(const short8*)(base + q * 8);                                \
    short8 b1 = *(const short8*)(base + 32 + q * 8);                           \
    short8 b2 = *(const short8*)(base + 64 + q * 8);                           \
    floatx4 gi = __builtin_amdgcn_mfma_f32_16x16x32_bf16(wA[0][0], b0, zacc, 0, 0, 0); \
    floatx4 gf = __builtin_amdgcn_mfma_f32_16x16x32_bf16(wA[1][0], b0, zacc, 0, 0, 0); \
    floatx4 gg = __builtin_amdgcn_mfma_f32_16x16x32_bf16(wA[2][0], b0, zacc, 0, 0, 0); \
    floatx4 go = __builtin_amdgcn_mfma_f32_16x16x32_bf16(wA[3][0], b0, zacc, 0, 0, 0); \
    gi = __builtin_amdgcn_mfma_f32_16x16x32_bf16(wA[0][1], b1, gi, 0, 0, 0);   \
    gf = __builtin_amdgcn_mfma_f32_16x16x32_bf16(wA[1][1], b1, gf, 0, 0, 0);   \
    gg = __builtin_amdgcn_mfma_f32_16x16x32_bf16(wA[2][1], b1, gg, 0, 0, 0);   \
    go = __builtin_amdgcn_mfma_f32_16x16x32_bf16(wA[3][1], b1, go, 0, 0, 0);   \
    gi = __builtin_amdgcn_mfma_f32_16x16x32_bf16(wA[0][2], b2, gi, 0, 0, 0);   \
    gf = __builtin_amdgcn_mfma_f32_16x16x32_bf16(wA[1][2], b2, gf, 0, 0, 0);   \
    gg = __builtin_amdgcn_mfma_f32_16x16x32_bf16(wA[2][2], b2, gg, 0, 0, 0);   \
    go = __builtin_amdgcn_mfma_f32_16x16x32_bf16(wA[3][2], b2, go, 0, 0, 0);   \
    float hv[4];                                                               \
    _Pragma("unroll") for (int r = 0; r < 4; ++r) {                            \
      float di = 1.0f + __builtin_amdgcn_exp2f(gi[r]);                         \
      float df = 1.0f + __builtin_amdgcn_exp2f(gf[r]);                         \
      float dg = 1.0f + __builtin_amdgcn_exp2f(gg[r]);                         \
      float dq = 1.0f + __builtin_amdgcn_exp2f(go[r]);                         \
      float pa = di * df, pb = dg * dq;                                        \
      float rp = __builtin_amdgcn_rcpf(pa * pb);                               \
      float iv = rp * df * pb;                                                 \
      float fv = rp * di * pb;                                                 \
      float t1 = rp * pa;                                                      \
      float gv = fmaf(-2.0f, t1 * dq, 1.0f);                                   \
      float ov = t1 * dg;                                                      \
      float cc = fmaf(fv, cst[G][NT][r], iv * gv);                             \
      cst[G][NT][r] = cc;                                                      \
      float dt = 1.0f + __builtin_amdgcn_exp2f(cc * TLOG2E);                   \
      float tc = fmaf(-2.0f, __builtin_amdgcn_rcpf(dt), 1.0f);                 \
      hv[r] = ov * tc;                                                         \
    }                                                                          \
    unsigned long long pk =                                                    \
        (unsigned long long)pk_bf16(hv[0], hv[1]) |                            \
        ((unsigned long long)pk_bf16(hv[2], hv[3]) << 32);                     \
    *(unsigned long long*)(HROW((G), (wb), srow) + wave * 16 + q * 4) = pk;    \
  } while (0)

#pragma unroll
  for (int t = 0; t < T_; ++t) {
    const int rb = t & 1, wb = rb ^ 1;
    if (t + 1 < T_) {
      unsigned pA = xpkA[(t + 1) >> 1], pB = xpkB[(t + 1) >> 1];
      short vA = (short)(((t + 1) & 1) ? (pA >> 16) : pA);
      short vB = (short)(((t + 1) & 1) ? (pB >> 16) : pB);
      HROW(0, wb, xseq)[64 + xc] = vA;
      HROW(1, wb, xseq)[64 + xc] = vB;
    }
    TILE(0, 0, rb, wb);
    TILE(1, 0, rb, wb);
    TILE(0, 1, rb, wb);
    TILE(1, 1, rb, wb);
    __syncthreads();
  }

  // ---- final FC: y = h_T @ W_fc^T + b_fc; h_T in buffer 0 of each group.
  // wave w -> group w>>1, tile w&1 (all 4 waves active) ----
  {
    short8 f0, f1;
    short8 z = {0, 0, 0, 0, 0, 0, 0, 0};
    if (m16 < 8) {
      const float* wr = W_fc + m16 * 64;
      f0 = load_w8s(wr + q * 8, 1.0f);
      f1 = load_w8s(wr + 32 + q * 8, 1.0f);
    } else {
      f0 = z;
      f1 = z;
    }
    const int grp = wave >> 1, mt = wave & 1;
    const int srow = mt * 16 + m16;
    const short* ar = HROW(grp, 0, srow);
    short8 h0 = *(const short8*)(ar + q * 8);
    short8 h1 = *(const short8*)(ar + 32 + q * 8);
    floatx4 acc = __builtin_amdgcn_mfma_f32_16x16x32_bf16(f0, h0, zacc, 0, 0, 0);
    acc = __builtin_amdgcn_mfma_f32_16x16x32_bf16(f1, h1, acc, 0, 0, 0);
    if (q < 2) {
      const int orow = blk * 64 + grp * 32 + srow;
#pragma unroll
      for (int r = 0; r < 4; ++r)
        out[orow * 8 + q * 4 + r] = acc[r] + b_fc[q * 4 + r];
    }
  }
}

extern "C" void kernel_launch(void* const* d_in, const int* in_sizes, int n_in,
                              void* d_out, int out_size, void* d_ws,
                              size_t ws_size, hipStream_t stream) {
  const float* x    = (const float*)d_in[0];
  const float* W_ih = (const float*)d_in[1];
  const float* W_hh = (const float*)d_in[2];
  const float* b_ih = (const float*)d_in[3];
  const float* b_hh = (const float*)d_in[4];
  const float* W_fc = (const float*)d_in[5];
  const float* b_fc = (const float*)d_in[6];
  float* out = (float*)d_out;
  hipLaunchKernelGGL(lstm_kernel, dim3(NBLK), dim3(256), 0, stream,
                     x, W_ih, W_hh, b_ih, b_hh, W_fc, b_fc, out);
}

// Round 7
// 178.708 us; speedup vs baseline: 1.0066x; 1.0066x over previous
//
#include <hip/hip_runtime.h>

#define T_ 12
#define N_ 1370
#define MSEQ 32      // sequences per block
#define LDH 72       // hbuf row stride in shorts (144B, 16B-aligned, 2-way banks)
#define HB (MSEQ * LDH)
#define NBLK 2740    // 87680 / 32

typedef __attribute__((ext_vector_type(8))) short short8;
typedef __attribute__((ext_vector_type(4))) float floatx4;

#define NLOG2E -1.4426950408889634f
#define TLOG2E 2.8853900817779268f

__device__ __forceinline__ short f2bf(float x) {
  unsigned u = __builtin_bit_cast(unsigned, x);
  u = (u + 0x7fffu + ((u >> 16) & 1u)) >> 16;
  return (short)u;
}
__device__ __forceinline__ unsigned pk_bf16(float a, float b) {
  unsigned r;
  asm("v_cvt_pk_bf16_f32 %0, %1, %2" : "=v"(r) : "v"(a), "v"(b));
  return r;
}
__device__ __forceinline__ short8 load_w8s(const float* __restrict__ p, float s) {
  short8 r;
#pragma unroll
  for (int j = 0; j < 8; ++j) r[j] = f2bf(p[j] * s);
  return r;
}

// R5 structure (MSEQ=32, 4 waves, 2740 blocks) with a register diet to fit
// (256,5) legitimately (R4/R5 A-B showed unified usage ~104 vs cap 102):
// x lives in a STATIC 12-step LDS tensor written once in the prologue
// (frees 6 xpk VGPRs + per-step extraction), hbuf holds h only (LDA 72).
// Swapped-operand MFMA: A = weights (m = gate row), B tiles: b0/b1 = h
// k-chunks from hbuf, b2 = [x(8) | 1.0 | 0...] from xls. Chunk2 A rows:
// q=0 -> W_ih (k=64..71), q=1 j=0 -> scaled bias (k=72), others ZERO ->
// whatever B holds there is multiplied by zero. D: col=lane&15 = seq,
// row=q*4+r = unit -> i/f/g/o of a cell share reg r; c stays fp32 in regs;
// h writeback = one ds_write_b64. Scales pre-folded: i,f,o rows by -log2e
// (sigma = 1/(1+2^y)), g rows by 2*log2e (tanh = 1 - 2/(1+2^y)); one v_rcp
// serves all 4 gates of a cell.
__global__ void __launch_bounds__(256, 5) lstm_kernel(
    const float* __restrict__ x, const float* __restrict__ W_ih,
    const float* __restrict__ W_hh, const float* __restrict__ b_ih,
    const float* __restrict__ b_hh, const float* __restrict__ W_fc,
    const float* __restrict__ b_fc, float* __restrict__ out) {
  __shared__ short hbuf[2 * HB];        // [buf][row][LDH], h in cols 0..63
  __shared__ short xls[T_][MSEQ][16];   // [t][seq][0..7]=x, [8]=1.0, rest 0

  const int tid = threadIdx.x;
  const int wave = tid >> 6;
  const int lane = tid & 63;
  const int m16 = lane & 15;
  const int q = lane >> 4;
  const int blk = blockIdx.x;

  // ---- A-operand weight fragments: lane row = gate unit wave*16+m16 ----
  const int urow = wave * 16 + m16;
  short8 wA[4][3];
#pragma unroll
  for (int g = 0; g < 4; ++g) {
    const float sg = (g == 2) ? TLOG2E : NLOG2E;
    const int grow = g * 64 + urow;
    const float* wr = W_hh + grow * 64;
    wA[g][0] = load_w8s(wr + q * 8, sg);
    wA[g][1] = load_w8s(wr + 32 + q * 8, sg);
    short8 z = {0, 0, 0, 0, 0, 0, 0, 0};
    if (q == 0) {
      wA[g][2] = load_w8s(W_ih + grow * 8, sg);      // k = 64..71: x cols
    } else if (q == 1) {
      z[0] = f2bf(sg * (b_ih[grow] + b_hh[grow]));   // k = 72: bias col
      wA[g][2] = z;
    } else {
      wA[g][2] = z;                                  // k = 80..95 dead
    }
  }

  // ---- zero hbuf (h0 = 0); fill xls: x (bf16), 1.0 col, zero pad ----
  {
    int* hp = (int*)hbuf;
#pragma unroll
    for (int i = tid; i < HB; i += 256) hp[i] = 0;  // 2*HB shorts = HB ints
  }
  {
    const int xseq = tid >> 3, xc = tid & 7;
    const int s0 = blk * MSEQ + xseq;
    const int bidx = s0 / N_;
    const int nidx = s0 - bidx * N_;
    const float* xp = x + ((size_t)(bidx * T_) * N_ + nidx) * 8 + xc;
#pragma unroll
    for (int t = 0; t < T_; ++t) {
      xls[t][xseq][xc] = f2bf(xp[(size_t)t * (N_ * 8)]);
      if (xc == 0) {
        xls[t][xseq][8] = (short)0x3F80;  // bf16 1.0
        xls[t][xseq][9] = 0;
        *(int*)&xls[t][xseq][10] = 0;
        *(int*)&xls[t][xseq][12] = 0;
        *(int*)&xls[t][xseq][14] = 0;
      }
    }
  }
  __syncthreads();

  const floatx4 zacc = {0.0f, 0.0f, 0.0f, 0.0f};
  const int xoff = q ? 8 : 0;  // q>=1 lanes read the [1.0,0..] region
  float cst[2][4];
#pragma unroll
  for (int nt = 0; nt < 2; ++nt)
#pragma unroll
    for (int r = 0; r < 4; ++r) cst[nt][r] = 0.0f;

#pragma unroll
  for (int t = 0; t < T_; ++t) {
    const short* rbuf = hbuf + (t & 1) * HB;
    short* wbuf = hbuf + ((t & 1) ^ 1) * HB;
#pragma unroll
    for (int nt = 0; nt < 2; ++nt) {
      const int srow = nt * 16 + m16;
      const short* base = rbuf + srow * LDH;
      short8 b0 = *(const short8*)(base + q * 8);
      short8 b1 = *(const short8*)(base + 32 + q * 8);
      short8 b2 = *(const short8*)&xls[t][srow][xoff];
      floatx4 gi = __builtin_amdgcn_mfma_f32_16x16x32_bf16(wA[0][0], b0, zacc, 0, 0, 0);
      floatx4 gf = __builtin_amdgcn_mfma_f32_16x16x32_bf16(wA[1][0], b0, zacc, 0, 0, 0);
      floatx4 gg = __builtin_amdgcn_mfma_f32_16x16x32_bf16(wA[2][0], b0, zacc, 0, 0, 0);
      floatx4 go = __builtin_amdgcn_mfma_f32_16x16x32_bf16(wA[3][0], b0, zacc, 0, 0, 0);
      gi = __builtin_amdgcn_mfma_f32_16x16x32_bf16(wA[0][1], b1, gi, 0, 0, 0);
      gf = __builtin_amdgcn_mfma_f32_16x16x32_bf16(wA[1][1], b1, gf, 0, 0, 0);
      gg = __builtin_amdgcn_mfma_f32_16x16x32_bf16(wA[2][1], b1, gg, 0, 0, 0);
      go = __builtin_amdgcn_mfma_f32_16x16x32_bf16(wA[3][1], b1, go, 0, 0, 0);
      gi = __builtin_amdgcn_mfma_f32_16x16x32_bf16(wA[0][2], b2, gi, 0, 0, 0);
      gf = __builtin_amdgcn_mfma_f32_16x16x32_bf16(wA[1][2], b2, gf, 0, 0, 0);
      gg = __builtin_amdgcn_mfma_f32_16x16x32_bf16(wA[2][2], b2, gg, 0, 0, 0);
      go = __builtin_amdgcn_mfma_f32_16x16x32_bf16(wA[3][2], b2, go, 0, 0, 0);
      float hv[4];
#pragma unroll
      for (int r = 0; r < 4; ++r) {
        float di = 1.0f + __builtin_amdgcn_exp2f(gi[r]);
        float df = 1.0f + __builtin_amdgcn_exp2f(gf[r]);
        float dg = 1.0f + __builtin_amdgcn_exp2f(gg[r]);
        float dq = 1.0f + __builtin_amdgcn_exp2f(go[r]);
        float pa = di * df, pb = dg * dq;
        float rp = __builtin_amdgcn_rcpf(pa * pb);
        float iv = rp * df * pb;                      // sigma(i)
        float fv = rp * di * pb;                      // sigma(f)
        float t1 = rp * pa;
        float gv = fmaf(-2.0f, t1 * dq, 1.0f);        // tanh(g)
        float ov = t1 * dg;                           // sigma(o)
        float cc = fmaf(fv, cst[nt][r], iv * gv);
        cst[nt][r] = cc;
        float dt = 1.0f + __builtin_amdgcn_exp2f(cc * TLOG2E);
        float tc = fmaf(-2.0f, __builtin_amdgcn_rcpf(dt), 1.0f);
        hv[r] = ov * tc;
      }
      unsigned long long pk =
          (unsigned long long)pk_bf16(hv[0], hv[1]) |
          ((unsigned long long)pk_bf16(hv[2], hv[3]) << 32);
      *(unsigned long long*)(wbuf + srow * LDH + wave * 16 + q * 4) = pk;
    }
    __syncthreads();
  }

  // ---- final FC: y = h_T @ W_fc^T + b_fc; h_T in buffer 0 ----
  if (wave < 2) {
    short8 f0, f1;
    short8 z = {0, 0, 0, 0, 0, 0, 0, 0};
    if (m16 < 8) {
      const float* wr = W_fc + m16 * 64;
      f0 = load_w8s(wr + q * 8, 1.0f);
      f1 = load_w8s(wr + 32 + q * 8, 1.0f);
    } else {
      f0 = z;
      f1 = z;
    }
    const int srow = wave * 16 + m16;
    short8 h0 = *(const short8*)&hbuf[srow * LDH + q * 8];
    short8 h1 = *(const short8*)&hbuf[srow * LDH + 32 + q * 8];
    floatx4 acc = __builtin_amdgcn_mfma_f32_16x16x32_bf16(f0, h0, zacc, 0, 0, 0);
    acc = __builtin_amdgcn_mfma_f32_16x16x32_bf16(f1, h1, acc, 0, 0, 0);
    if (q < 2) {
      const int orow = blk * MSEQ + srow;
#pragma unroll
      for (int r = 0; r < 4; ++r)
        out[orow * 8 + q * 4 + r] = acc[r] + b_fc[q * 4 + r];
    }
  }
}

extern "C" void kernel_launch(void* const* d_in, const int* in_sizes, int n_in,
                              void* d_out, int out_size, void* d_ws,
                              size_t ws_size, hipStream_t stream) {
  const float* x    = (const float*)d_in[0];
  const float* W_ih = (const float*)d_in[1];
  const float* W_hh = (const float*)d_in[2];
  const float* b_ih = (const float*)d_in[3];
  const float* b_hh = (const float*)d_in[4];
  const float* W_fc = (const float*)d_in[5];
  const float* b_fc = (const float*)d_in[6];
  float* out = (float*)d_out;
  hipLaunchKernelGGL(lstm_kernel, dim3(NBLK), dim3(256), 0, stream,
                     x, W_ih, W_hh, b_ih, b_hh, W_fc, b_fc, out);
}

// Round 8
// 174.942 us; speedup vs baseline: 1.0283x; 1.0215x over previous
//
#include <hip/hip_runtime.h>

#define T_ 12
#define N_ 1370
#define MSEQ 32      // sequences per block
#define LDH 72       // hbuf row stride in shorts (144B, 16B-aligned, 2-way banks)
#define HB (MSEQ * LDH)
#define NBLK 2740    // 87680 / 32

typedef __attribute__((ext_vector_type(8))) short short8;
typedef __attribute__((ext_vector_type(4))) float floatx4;

#define NLOG2E -1.4426950408889634f
#define TLOG2E 2.8853900817779268f

__device__ __forceinline__ short f2bf(float x) {
  unsigned u = __builtin_bit_cast(unsigned, x);
  u = (u + 0x7fffu + ((u >> 16) & 1u)) >> 16;
  return (short)u;
}
__device__ __forceinline__ unsigned pk_bf16(float a, float b) {
  unsigned r;
  asm("v_cvt_pk_bf16_f32 %0, %1, %2" : "=v"(r) : "v"(a), "v"(b));
  return r;
}
__device__ __forceinline__ short8 load_w8s(const float* __restrict__ p, float s) {
  short8 r;
#pragma unroll
  for (int j = 0; j < 8; ++j) r[j] = f2bf(p[j] * s);
  return r;
}

// R5/R7 hybrid: MSEQ=32, 4 waves, 2740 blocks, bounds (256,4) — (256,5)
// caps at 96 regs (512/5 rounded down to 8) and spilled in R4/R7; unified
// watermark is ~104+. Static xls (x staged once, never restaged); hbuf holds
// h only. Swapped-operand MFMA: A = weights (m = gate row), B: b0/b1 = h
// k-chunks from hbuf, b2 = [x(8)|1.0|0..] from xls. Chunk2 A rows: q=0 ->
// W_ih, q=1 j=0 -> scaled bias, others ZERO (pad reads harmless).
// D: col=lane&15 = seq, row=q*4+r = unit; c stays fp32 in regs; h writeback
// one ds_write_b64. Scales pre-folded: i,f,o by -log2e (sigma=1/(1+2^y)),
// g by 2*log2e (tanh=1-2/(1+2^y)).
// NEW: rcp grouping widened — gates 8-way across cell pairs (worst-case
// product ~2^70 << fp32 max), tanh(c) 2-way (|c|<~12 -> product <2^70).
// Trans/step: 56 -> 48 (saves ~128 cyc/step of the ~1330 busy).
__global__ void __launch_bounds__(256, 4) lstm_kernel(
    const float* __restrict__ x, const float* __restrict__ W_ih,
    const float* __restrict__ W_hh, const float* __restrict__ b_ih,
    const float* __restrict__ b_hh, const float* __restrict__ W_fc,
    const float* __restrict__ b_fc, float* __restrict__ out) {
  __shared__ short hbuf[2 * HB];        // [buf][row][LDH], h in cols 0..63
  __shared__ short xls[T_][MSEQ][16];   // [t][seq][0..7]=x, [8]=1.0, rest 0

  const int tid = threadIdx.x;
  const int wave = tid >> 6;
  const int lane = tid & 63;
  const int m16 = lane & 15;
  const int q = lane >> 4;
  const int blk = blockIdx.x;

  // ---- A-operand weight fragments: lane row = gate unit wave*16+m16 ----
  const int urow = wave * 16 + m16;
  short8 wA[4][3];
#pragma unroll
  for (int g = 0; g < 4; ++g) {
    const float sg = (g == 2) ? TLOG2E : NLOG2E;
    const int grow = g * 64 + urow;
    const float* wr = W_hh + grow * 64;
    wA[g][0] = load_w8s(wr + q * 8, sg);
    wA[g][1] = load_w8s(wr + 32 + q * 8, sg);
    short8 z = {0, 0, 0, 0, 0, 0, 0, 0};
    if (q == 0) {
      wA[g][2] = load_w8s(W_ih + grow * 8, sg);      // k = 64..71: x cols
    } else if (q == 1) {
      z[0] = f2bf(sg * (b_ih[grow] + b_hh[grow]));   // k = 72: bias col
      wA[g][2] = z;
    } else {
      wA[g][2] = z;                                  // k = 80..95 dead
    }
  }

  // ---- zero hbuf (h0 = 0); fill xls: x (bf16), 1.0 col, zero pad ----
  {
    int* hp = (int*)hbuf;
#pragma unroll
    for (int i = tid; i < HB; i += 256) hp[i] = 0;  // 2*HB shorts = HB ints
  }
  {
    const int xseq = tid >> 3, xc = tid & 7;
    const int s0 = blk * MSEQ + xseq;
    const int bidx = s0 / N_;
    const int nidx = s0 - bidx * N_;
    const float* xp = x + ((size_t)(bidx * T_) * N_ + nidx) * 8 + xc;
#pragma unroll
    for (int t = 0; t < T_; ++t) {
      xls[t][xseq][xc] = f2bf(xp[(size_t)t * (N_ * 8)]);
      if (xc == 0) {
        xls[t][xseq][8] = (short)0x3F80;  // bf16 1.0
        xls[t][xseq][9] = 0;
        *(int*)&xls[t][xseq][10] = 0;
        *(int*)&xls[t][xseq][12] = 0;
        *(int*)&xls[t][xseq][14] = 0;
      }
    }
  }
  __syncthreads();

  const floatx4 zacc = {0.0f, 0.0f, 0.0f, 0.0f};
  const int xoff = q ? 8 : 0;  // q>=1 lanes read the [1.0,0..] region
  float cst[2][4];
#pragma unroll
  for (int nt = 0; nt < 2; ++nt)
#pragma unroll
    for (int r = 0; r < 4; ++r) cst[nt][r] = 0.0f;

#pragma unroll
  for (int t = 0; t < T_; ++t) {
    const short* rbuf = hbuf + (t & 1) * HB;
    short* wbuf = hbuf + ((t & 1) ^ 1) * HB;
#pragma unroll
    for (int nt = 0; nt < 2; ++nt) {
      const int srow = nt * 16 + m16;
      const short* base = rbuf + srow * LDH;
      short8 b0 = *(const short8*)(base + q * 8);
      short8 b1 = *(const short8*)(base + 32 + q * 8);
      short8 b2 = *(const short8*)&xls[t][srow][xoff];
      floatx4 gi = __builtin_amdgcn_mfma_f32_16x16x32_bf16(wA[0][0], b0, zacc, 0, 0, 0);
      floatx4 gf = __builtin_amdgcn_mfma_f32_16x16x32_bf16(wA[1][0], b0, zacc, 0, 0, 0);
      floatx4 gg = __builtin_amdgcn_mfma_f32_16x16x32_bf16(wA[2][0], b0, zacc, 0, 0, 0);
      floatx4 go = __builtin_amdgcn_mfma_f32_16x16x32_bf16(wA[3][0], b0, zacc, 0, 0, 0);
      gi = __builtin_amdgcn_mfma_f32_16x16x32_bf16(wA[0][1], b1, gi, 0, 0, 0);
      gf = __builtin_amdgcn_mfma_f32_16x16x32_bf16(wA[1][1], b1, gf, 0, 0, 0);
      gg = __builtin_amdgcn_mfma_f32_16x16x32_bf16(wA[2][1], b1, gg, 0, 0, 0);
      go = __builtin_amdgcn_mfma_f32_16x16x32_bf16(wA[3][1], b1, go, 0, 0, 0);
      gi = __builtin_amdgcn_mfma_f32_16x16x32_bf16(wA[0][2], b2, gi, 0, 0, 0);
      gf = __builtin_amdgcn_mfma_f32_16x16x32_bf16(wA[1][2], b2, gf, 0, 0, 0);
      gg = __builtin_amdgcn_mfma_f32_16x16x32_bf16(wA[2][2], b2, gg, 0, 0, 0);
      go = __builtin_amdgcn_mfma_f32_16x16x32_bf16(wA[3][2], b2, go, 0, 0, 0);
      float hv[4];
      // cell pairs (r0, r0+1): one rcp for 8 gate denoms, one for 2 tanh(c)
#pragma unroll
      for (int rp = 0; rp < 2; ++rp) {
        const int r0 = 2 * rp, r1 = r0 + 1;
        float di0 = 1.0f + __builtin_amdgcn_exp2f(gi[r0]);
        float df0 = 1.0f + __builtin_amdgcn_exp2f(gf[r0]);
        float dg0 = 1.0f + __builtin_amdgcn_exp2f(gg[r0]);
        float dq0 = 1.0f + __builtin_amdgcn_exp2f(go[r0]);
        float di1 = 1.0f + __builtin_amdgcn_exp2f(gi[r1]);
        float df1 = 1.0f + __builtin_amdgcn_exp2f(gf[r1]);
        float dg1 = 1.0f + __builtin_amdgcn_exp2f(gg[r1]);
        float dq1 = 1.0f + __builtin_amdgcn_exp2f(go[r1]);
        float pa0 = di0 * df0, pb0 = dg0 * dq0, P0 = pa0 * pb0;
        float pa1 = di1 * df1, pb1 = dg1 * dq1, P1 = pa1 * pb1;
        float rp8 = __builtin_amdgcn_rcpf(P0 * P1);
        float rc0 = rp8 * P1;  // 1/P0
        float rc1 = rp8 * P0;  // 1/P1
        float iv0 = rc0 * df0 * pb0, fv0 = rc0 * di0 * pb0;
        float t10 = rc0 * pa0;
        float gv0 = fmaf(-2.0f, t10 * dq0, 1.0f);
        float ov0 = t10 * dg0;
        float iv1 = rc1 * df1 * pb1, fv1 = rc1 * di1 * pb1;
        float t11 = rc1 * pa1;
        float gv1 = fmaf(-2.0f, t11 * dq1, 1.0f);
        float ov1 = t11 * dg1;
        float cc0 = fmaf(fv0, cst[nt][r0], iv0 * gv0);
        float cc1 = fmaf(fv1, cst[nt][r1], iv1 * gv1);
        cst[nt][r0] = cc0;
        cst[nt][r1] = cc1;
        float dt0 = 1.0f + __builtin_amdgcn_exp2f(cc0 * TLOG2E);
        float dt1 = 1.0f + __builtin_amdgcn_exp2f(cc1 * TLOG2E);
        float rt = __builtin_amdgcn_rcpf(dt0 * dt1);
        hv[r0] = ov0 * fmaf(-2.0f, rt * dt1, 1.0f);
        hv[r1] = ov1 * fmaf(-2.0f, rt * dt0, 1.0f);
      }
      unsigned long long pk =
          (unsigned long long)pk_bf16(hv[0], hv[1]) |
          ((unsigned long long)pk_bf16(hv[2], hv[3]) << 32);
      *(unsigned long long*)(wbuf + srow * LDH + wave * 16 + q * 4) = pk;
    }
    __syncthreads();
  }

  // ---- final FC: y = h_T @ W_fc^T + b_fc; h_T in buffer 0 ----
  if (wave < 2) {
    short8 f0, f1;
    short8 z = {0, 0, 0, 0, 0, 0, 0, 0};
    if (m16 < 8) {
      const float* wr = W_fc + m16 * 64;
      f0 = load_w8s(wr + q * 8, 1.0f);
      f1 = load_w8s(wr + 32 + q * 8, 1.0f);
    } else {
      f0 = z;
      f1 = z;
    }
    const int srow = wave * 16 + m16;
    short8 h0 = *(const short8*)&hbuf[srow * LDH + q * 8];
    short8 h1 = *(const short8*)&hbuf[srow * LDH + 32 + q * 8];
    floatx4 acc = __builtin_amdgcn_mfma_f32_16x16x32_bf16(f0, h0, zacc, 0, 0, 0);
    acc = __builtin_amdgcn_mfma_f32_16x16x32_bf16(f1, h1, acc, 0, 0, 0);
    if (q < 2) {
      const int orow = blk * MSEQ + srow;
#pragma unroll
      for (int r = 0; r < 4; ++r)
        out[orow * 8 + q * 4 + r] = acc[r] + b_fc[q * 4 + r];
    }
  }
}

extern "C" void kernel_launch(void* const* d_in, const int* in_sizes, int n_in,
                              void* d_out, int out_size, void* d_ws,
                              size_t ws_size, hipStream_t stream) {
  const float* x    = (const float*)d_in[0];
  const float* W_ih = (const float*)d_in[1];
  const float* W_hh = (const float*)d_in[2];
  const float* b_ih = (const float*)d_in[3];
  const float* b_hh = (const float*)d_in[4];
  const float* W_fc = (const float*)d_in[5];
  const float* b_fc = (const float*)d_in[6];
  float* out = (float*)d_out;
  hipLaunchKernelGGL(lstm_kernel, dim3(NBLK), dim3(256), 0, stream,
                     x, W_ih, W_hh, b_ih, b_hh, W_fc, b_fc, out);
}